// Round 1
// baseline (540.651 us; speedup 1.0000x reference)
//
#include <hip/hip_runtime.h>

#define N_NODES 100000
#define N_EDGES 1600000
#define D 64

// One wave (64 lanes) per edge; lane d handles feature dim d.
// edge_src/dst/val loads are wave-uniform; x gather + atomic dst are coalesced 256B.
__global__ __launch_bounds__(256) void gin_scatter(
    const float* __restrict__ x,
    const int* __restrict__ esrc,
    const int* __restrict__ edst,
    const float* __restrict__ eval_,
    float* __restrict__ agg)  // [N_NODES][D], pre-zeroed
{
    int tid = blockIdx.x * 256 + threadIdx.x;
    int e = tid >> 6;
    if (e >= N_EDGES) return;
    int d = tid & 63;
    int s = esrc[e];
    int t = edst[e];
    float v = eval_[e];
    atomicAdd(&agg[(size_t)s * D + d], v * x[(size_t)t * D + d]);
}

// One wave per node row: rep = agg + eps*x (in place), out = rep @ W + bias.
// W staged in LDS; lane j owns output column j; rep row broadcast via shuffles.
__global__ __launch_bounds__(256) void gin_finalize(
    const float* __restrict__ x,
    const float* __restrict__ weight,   // [D][D] row-major: weight[k*D + j]
    const float* __restrict__ epsilon,  // [1]
    const float* __restrict__ bias,     // [D]
    float* __restrict__ out,            // [N_NODES][D]
    float* __restrict__ rep)            // [N_NODES][D], holds agg on entry
{
    __shared__ float Ws[D * D];
    __shared__ float bs[D];
    int t = threadIdx.x;
    #pragma unroll
    for (int i = 0; i < (D * D) / 256; ++i)
        Ws[t + i * 256] = weight[t + i * 256];
    if (t < D) bs[t] = bias[t];
    __syncthreads();

    float eps = epsilon[0];
    int wave = t >> 6;
    int lane = t & 63;
    int row = blockIdx.x * 4 + wave;
    if (row >= N_NODES) return;

    size_t base = (size_t)row * D;
    float r = rep[base + lane] + eps * x[base + lane];
    rep[base + lane] = r;

    float acc = bs[lane];
    #pragma unroll
    for (int k = 0; k < D; ++k) {
        float rk = __shfl(r, k, 64);
        acc += rk * Ws[k * D + lane];  // stride-1 across lanes: 2-way alias, free
    }
    out[base + lane] = acc;
}

extern "C" void kernel_launch(void* const* d_in, const int* in_sizes, int n_in,
                              void* d_out, int out_size, void* d_ws, size_t ws_size,
                              hipStream_t stream) {
    const float* x     = (const float*)d_in[0];
    const int*   esrc  = (const int*)  d_in[1];
    const int*   edst  = (const int*)  d_in[2];
    const float* ev    = (const float*)d_in[3];
    const float* w     = (const float*)d_in[4];
    const float* eps   = (const float*)d_in[5];
    const float* bias  = (const float*)d_in[6];

    float* out = (float*)d_out;                       // first 6.4M floats
    float* rep = out + (size_t)N_NODES * D;           // second 6.4M floats (agg accumulator)

    // d_out is poisoned 0xAA each launch — zero the accumulator half.
    hipMemsetAsync(rep, 0, (size_t)N_NODES * D * sizeof(float), stream);

    int scatter_items = N_EDGES * 64;                 // 102,400,000 (< 2^31)
    gin_scatter<<<(scatter_items + 255) / 256, 256, 0, stream>>>(x, esrc, edst, ev, rep);

    gin_finalize<<<N_NODES / 4, 256, 0, stream>>>(x, w, eps, bias, out, rep);
}

// Round 2
// 437.247 us; speedup vs baseline: 1.2365x; 1.2365x over previous
//
#include <hip/hip_runtime.h>

#define N_NODES 100000
#define N_EDGES 1600000
#define D 64
#define SCAN_BLOCK 1024
#define N_CHUNKS ((N_NODES + SCAN_BLOCK - 1) / SCAN_BLOCK)  // 98

// ---- ws layout (4-byte units) ----
// [0, 100000)          cur   (fill cursors, zeroed)
// [100000, 200000)     cnt   (histogram, zeroed)     -- contiguous with cur: one memset
// [200000, 300001)     row_ptr
// [300002, 300130)     partial (128, 8B-aligned start not needed: ints)
// [300160, 3500160)    pairs: int2[N_EDGES] (dst, val bits) -- offset even => 8B aligned
#define WS_CUR      0
#define WS_CNT      100000
#define WS_ROWPTR   200000
#define WS_PARTIAL  300032
#define WS_PAIRS    300160

__global__ __launch_bounds__(256) void k_hist(
    const int* __restrict__ esrc, int* __restrict__ cnt)
{
    int e = blockIdx.x * 256 + threadIdx.x;
    if (e < N_EDGES) atomicAdd(&cnt[esrc[e]], 1);
}

// per-chunk sums of cnt -> partial[chunk]
__global__ __launch_bounds__(SCAN_BLOCK) void k_chunk_sum(
    const int* __restrict__ cnt, int* __restrict__ partial)
{
    __shared__ int s[16];
    int t = threadIdx.x;
    int i = blockIdx.x * SCAN_BLOCK + t;
    int v = (i < N_NODES) ? cnt[i] : 0;
    #pragma unroll
    for (int off = 32; off; off >>= 1) v += __shfl_down(v, off, 64);
    if ((t & 63) == 0) s[t >> 6] = v;
    __syncthreads();
    if (t < 16) {
        int w = s[t];
        #pragma unroll
        for (int off = 8; off; off >>= 1) w += __shfl_down(w, off, 16);
        if (t == 0) partial[blockIdx.x] = w;
    }
}

// exclusive scan of partial[0..N_CHUNKS) in place; writes row_ptr[N_NODES]=total
__global__ __launch_bounds__(128) void k_scan_partial(
    int* __restrict__ partial, int* __restrict__ row_ptr)
{
    __shared__ int s[128];
    int t = threadIdx.x;
    int v = (t < N_CHUNKS) ? partial[t] : 0;
    s[t] = v;
    __syncthreads();
    #pragma unroll
    for (int off = 1; off < 128; off <<= 1) {
        int y = (t >= off) ? s[t - off] : 0;
        __syncthreads();
        s[t] += y;
        __syncthreads();
    }
    if (t < N_CHUNKS) partial[t] = s[t] - v;   // exclusive
    if (t == 127) row_ptr[N_NODES] = s[127];   // == N_EDGES
}

// per-chunk inclusive scan of cnt + chunk base -> row_ptr (exclusive global scan)
__global__ __launch_bounds__(SCAN_BLOCK) void k_chunk_scan(
    const int* __restrict__ cnt, const int* __restrict__ partial,
    int* __restrict__ row_ptr)
{
    __shared__ int s[SCAN_BLOCK];
    int t = threadIdx.x;
    int i = blockIdx.x * SCAN_BLOCK + t;
    int v = (i < N_NODES) ? cnt[i] : 0;
    s[t] = v;
    __syncthreads();
    #pragma unroll
    for (int off = 1; off < SCAN_BLOCK; off <<= 1) {
        int y = (t >= off) ? s[t - off] : 0;
        __syncthreads();
        s[t] += y;
        __syncthreads();
    }
    if (i < N_NODES) row_ptr[i] = partial[blockIdx.x] + s[t] - v;
}

__global__ __launch_bounds__(256) void k_fill(
    const int* __restrict__ esrc, const int* __restrict__ edst,
    const float* __restrict__ eval_, const int* __restrict__ row_ptr,
    int* __restrict__ cur, int2* __restrict__ pairs)
{
    int e = blockIdx.x * 256 + threadIdx.x;
    if (e >= N_EDGES) return;
    int s = esrc[e];
    int pos = row_ptr[s] + atomicAdd(&cur[s], 1);
    pairs[pos] = make_int2(edst[e], __float_as_int(eval_[e]));
}

// One wave per node: register-accumulate gather, then rep + GEMV epilogue.
__global__ __launch_bounds__(256) void k_gather(
    const float* __restrict__ x, const int* __restrict__ row_ptr,
    const int2* __restrict__ pairs,
    const float* __restrict__ weight, const float* __restrict__ epsilon,
    const float* __restrict__ bias,
    float* __restrict__ out, float* __restrict__ rep)
{
    __shared__ float Ws[D * D];
    __shared__ float bs[D];
    int t = threadIdx.x;
    #pragma unroll
    for (int i = 0; i < (D * D) / 256; ++i)
        Ws[t + i * 256] = weight[t + i * 256];
    if (t < D) bs[t] = bias[t];
    __syncthreads();

    int wave = t >> 6;
    int lane = t & 63;
    int row = blockIdx.x * 4 + wave;
    if (row >= N_NODES) return;

    int start = row_ptr[row];
    int end   = row_ptr[row + 1];
    float acc = 0.0f;
    for (int j = start; j < end; ++j) {
        int2 p = pairs[j];                       // wave-uniform 8B, L1 broadcast
        acc += __int_as_float(p.y) * x[(size_t)p.x * D + lane];  // coalesced 256B gather
    }

    size_t base = (size_t)row * D;
    float r = acc + epsilon[0] * x[base + lane];
    rep[base + lane] = r;

    float o = bs[lane];
    #pragma unroll
    for (int k = 0; k < D; ++k)
        o += __shfl(r, k, 64) * Ws[k * D + lane];
    out[base + lane] = o;
}

extern "C" void kernel_launch(void* const* d_in, const int* in_sizes, int n_in,
                              void* d_out, int out_size, void* d_ws, size_t ws_size,
                              hipStream_t stream) {
    const float* x    = (const float*)d_in[0];
    const int*   esrc = (const int*)  d_in[1];
    const int*   edst = (const int*)  d_in[2];
    const float* ev   = (const float*)d_in[3];
    const float* w    = (const float*)d_in[4];
    const float* eps  = (const float*)d_in[5];
    const float* bias = (const float*)d_in[6];

    float* out = (float*)d_out;
    float* rep = out + (size_t)N_NODES * D;

    int*  ws      = (int*)d_ws;
    int*  cur     = ws + WS_CUR;
    int*  cnt     = ws + WS_CNT;
    int*  row_ptr = ws + WS_ROWPTR;
    int*  partial = ws + WS_PARTIAL;
    int2* pairs   = (int2*)(ws + WS_PAIRS);

    // zero cur + cnt (contiguous 800 KB)
    hipMemsetAsync(cur, 0, 2 * N_NODES * sizeof(int), stream);

    int egrid = (N_EDGES + 255) / 256;
    k_hist<<<egrid, 256, 0, stream>>>(esrc, cnt);
    k_chunk_sum<<<N_CHUNKS, SCAN_BLOCK, 0, stream>>>(cnt, partial);
    k_scan_partial<<<1, 128, 0, stream>>>(partial, row_ptr);
    k_chunk_scan<<<N_CHUNKS, SCAN_BLOCK, 0, stream>>>(cnt, partial, row_ptr);
    k_fill<<<egrid, 256, 0, stream>>>(esrc, edst, ev, row_ptr, cur, pairs);
    k_gather<<<N_NODES / 4, 256, 0, stream>>>(x, row_ptr, pairs, w, eps, bias, out, rep);
}

// Round 3
// 312.376 us; speedup vs baseline: 1.7308x; 1.3997x over previous
//
#include <hip/hip_runtime.h>

#define N_NODES 100000
#define N_EDGES 1600000
#define D 64
#define SCAN_BLOCK 1024
#define N_CHUNKS ((N_NODES + SCAN_BLOCK - 1) / SCAN_BLOCK)  // 98

// ---- ws layout (4-byte units) ----
#define WS_CNT      0         // [100000] histogram / rank cursors (zeroed)
#define WS_CUR      100000    // [100000] cursor-path fill cursors (zeroed, cursor path only)
#define WS_ROWPTR   200000    // [100001]
#define WS_PARTIAL  300032    // [128]
#define WS_RANK     300160    // [1600000]  (rank path only)
#define WS_PAIRS_R  1900160   // int2[1600000] rank path  -> needs 20,400,640 B
#define WS_PAIRS_C  300160    // int2[1600000] cursor path -> needs 14,000,640 B

// ---------------- CSR build ----------------

__global__ __launch_bounds__(256) void k_hist_rank(
    const int* __restrict__ esrc, int* __restrict__ cnt, int* __restrict__ rank)
{
    int e = blockIdx.x * 256 + threadIdx.x;
    if (e < N_EDGES) rank[e] = atomicAdd(&cnt[esrc[e]], 1);
}

__global__ __launch_bounds__(256) void k_hist(
    const int* __restrict__ esrc, int* __restrict__ cnt)
{
    int e = blockIdx.x * 256 + threadIdx.x;
    if (e < N_EDGES) atomicAdd(&cnt[esrc[e]], 1);
}

__global__ __launch_bounds__(SCAN_BLOCK) void k_chunk_sum(
    const int* __restrict__ cnt, int* __restrict__ partial)
{
    __shared__ int s[16];
    int t = threadIdx.x;
    int i = blockIdx.x * SCAN_BLOCK + t;
    int v = (i < N_NODES) ? cnt[i] : 0;
    #pragma unroll
    for (int off = 32; off; off >>= 1) v += __shfl_down(v, off, 64);
    if ((t & 63) == 0) s[t >> 6] = v;
    __syncthreads();
    if (t < 16) {
        int w = s[t];
        #pragma unroll
        for (int off = 8; off; off >>= 1) w += __shfl_down(w, off, 16);
        if (t == 0) partial[blockIdx.x] = w;
    }
}

// shuffle-based exclusive scan of partial[0..N_CHUNKS); row_ptr[N_NODES] = total
__global__ __launch_bounds__(128) void k_scan_partial(
    int* __restrict__ partial, int* __restrict__ row_ptr)
{
    __shared__ int w0;
    int t = threadIdx.x;
    int lane = t & 63;
    int v = (t < N_CHUNKS) ? partial[t] : 0;
    int s = v;
    #pragma unroll
    for (int off = 1; off < 64; off <<= 1) {
        int y = __shfl_up(s, off, 64);
        if (lane >= off) s += y;
    }
    if (t == 63) w0 = s;
    __syncthreads();
    if (t >= 64) s += w0;
    if (t < N_CHUNKS) partial[t] = s - v;          // exclusive
    if (t == N_CHUNKS - 1) row_ptr[N_NODES] = s;   // total == N_EDGES
}

// shuffle-based per-chunk scan: row_ptr[i] = chunk_base + exclusive_scan(cnt)
__global__ __launch_bounds__(SCAN_BLOCK) void k_chunk_scan(
    const int* __restrict__ cnt, const int* __restrict__ partial,
    int* __restrict__ row_ptr)
{
    __shared__ int wsum[16];
    int t = threadIdx.x;
    int lane = t & 63, wid = t >> 6;
    int i = blockIdx.x * SCAN_BLOCK + t;
    int v = (i < N_NODES) ? cnt[i] : 0;
    int s = v;
    #pragma unroll
    for (int off = 1; off < 64; off <<= 1) {
        int y = __shfl_up(s, off, 64);
        if (lane >= off) s += y;
    }
    if (lane == 63) wsum[wid] = s;
    __syncthreads();
    if (t < 16) {
        int w = wsum[t];
        #pragma unroll
        for (int off = 1; off < 16; off <<= 1) {
            int y = __shfl_up(w, off, 16);
            if (t >= off) w += y;
        }
        wsum[t] = w;
    }
    __syncthreads();
    int prefix = wid ? wsum[wid - 1] : 0;
    if (i < N_NODES) row_ptr[i] = partial[blockIdx.x] + prefix + s - v;
}

__global__ __launch_bounds__(256) void k_fill_rank(
    const int* __restrict__ esrc, const int* __restrict__ edst,
    const float* __restrict__ eval_, const int* __restrict__ row_ptr,
    const int* __restrict__ rank, int2* __restrict__ pairs)
{
    int e = blockIdx.x * 256 + threadIdx.x;
    if (e >= N_EDGES) return;
    int s = esrc[e];
    pairs[row_ptr[s] + rank[e]] = make_int2(edst[e], __float_as_int(eval_[e]));
}

__global__ __launch_bounds__(256) void k_fill_cur(
    const int* __restrict__ esrc, const int* __restrict__ edst,
    const float* __restrict__ eval_, const int* __restrict__ row_ptr,
    int* __restrict__ cur, int2* __restrict__ pairs)
{
    int e = blockIdx.x * 256 + threadIdx.x;
    if (e >= N_EDGES) return;
    int s = esrc[e];
    int pos = row_ptr[s] + atomicAdd(&cur[s], 1);
    pairs[pos] = make_int2(edst[e], __float_as_int(eval_[e]));
}

// ---------------- aggregation: rep = agg + eps*x ----------------
// One wave per row, grid-stride (16 rows/wave averages degree imbalance),
// edge loop unrolled x4 for ILP. No LDS, no epilogue.
#define GATHER_BLOCKS 1563

__global__ __launch_bounds__(256) void k_gather(
    const float* __restrict__ x, const int* __restrict__ row_ptr,
    const int2* __restrict__ pairs, const float* __restrict__ epsilon,
    float* __restrict__ rep)
{
    int gw = (blockIdx.x * 256 + threadIdx.x) >> 6;
    int lane = threadIdx.x & 63;
    int nw = gridDim.x * 4;
    float eps = epsilon[0];
    for (int row = gw; row < N_NODES; row += nw) {
        int start = __builtin_amdgcn_readfirstlane(row_ptr[row]);
        int end   = __builtin_amdgcn_readfirstlane(row_ptr[row + 1]);
        float acc = 0.0f;
        int j = start;
        for (; j + 4 <= end; j += 4) {
            int2 p0 = pairs[j];
            int2 p1 = pairs[j + 1];
            int2 p2 = pairs[j + 2];
            int2 p3 = pairs[j + 3];
            float a0 = x[(size_t)p0.x * D + lane];
            float a1 = x[(size_t)p1.x * D + lane];
            float a2 = x[(size_t)p2.x * D + lane];
            float a3 = x[(size_t)p3.x * D + lane];
            acc += __int_as_float(p0.y) * a0;
            acc += __int_as_float(p1.y) * a1;
            acc += __int_as_float(p2.y) * a2;
            acc += __int_as_float(p3.y) * a3;
        }
        for (; j < end; ++j) {
            int2 p = pairs[j];
            acc += __int_as_float(p.y) * x[(size_t)p.x * D + lane];
        }
        size_t base = (size_t)row * D;
        rep[base + lane] = acc + eps * x[base + lane];
    }
}

// ---------------- out = rep @ W + bias ----------------
// 4 waves/block, 8 rows/wave, lane j owns output column j.
// Ws[k*64+j] across lanes is stride-1 (2-way alias, free); rep loads are
// wave-uniform float4 (L1 broadcast).
__global__ __launch_bounds__(256) void k_gemm(
    const float* __restrict__ rep, const float* __restrict__ weight,
    const float* __restrict__ bias, float* __restrict__ out)
{
    __shared__ float Ws[D * D];
    int t = threadIdx.x;
    {
        const float4* w4 = (const float4*)weight;
        float4* s4 = (float4*)Ws;
        #pragma unroll
        for (int i = 0; i < (D * D / 4) / 256; ++i)
            s4[t + i * 256] = w4[t + i * 256];
    }
    __syncthreads();
    int wave = t >> 6, lane = t & 63;
    int row0 = blockIdx.x * 32 + wave * 8;
    float b = bias[lane];
    float acc[8];
    #pragma unroll
    for (int r = 0; r < 8; ++r) acc[r] = b;
    const float4* rep4 = (const float4*)rep;
    #pragma unroll 2
    for (int k4 = 0; k4 < 16; ++k4) {
        float4 rv[8];
        #pragma unroll
        for (int r = 0; r < 8; ++r)
            rv[r] = rep4[(size_t)(row0 + r) * 16 + k4];
        #pragma unroll
        for (int kk = 0; kk < 4; ++kk) {
            float w = Ws[(k4 * 4 + kk) * D + lane];
            #pragma unroll
            for (int r = 0; r < 8; ++r)
                acc[r] += ((const float*)&rv[r])[kk] * w;
        }
    }
    #pragma unroll
    for (int r = 0; r < 8; ++r)
        out[(size_t)(row0 + r) * D + lane] = acc[r];
}

extern "C" void kernel_launch(void* const* d_in, const int* in_sizes, int n_in,
                              void* d_out, int out_size, void* d_ws, size_t ws_size,
                              hipStream_t stream) {
    const float* x    = (const float*)d_in[0];
    const int*   esrc = (const int*)  d_in[1];
    const int*   edst = (const int*)  d_in[2];
    const float* ev   = (const float*)d_in[3];
    const float* w    = (const float*)d_in[4];
    const float* eps  = (const float*)d_in[5];
    const float* bias = (const float*)d_in[6];

    float* out = (float*)d_out;
    float* rep = out + (size_t)N_NODES * D;

    int* ws      = (int*)d_ws;
    int* cnt     = ws + WS_CNT;
    int* cur     = ws + WS_CUR;
    int* row_ptr = ws + WS_ROWPTR;
    int* partial = ws + WS_PARTIAL;

    bool rank_path = ws_size >= (size_t)(WS_PAIRS_R + 2 * N_EDGES) * sizeof(int);
    int* rank   = ws + WS_RANK;
    int2* pairs = (int2*)(ws + (rank_path ? WS_PAIRS_R : WS_PAIRS_C));

    int egrid = (N_EDGES + 255) / 256;

    if (rank_path) {
        hipMemsetAsync(cnt, 0, N_NODES * sizeof(int), stream);
        k_hist_rank<<<egrid, 256, 0, stream>>>(esrc, cnt, rank);
    } else {
        hipMemsetAsync(cnt, 0, 2 * N_NODES * sizeof(int), stream);  // cnt + cur
        k_hist<<<egrid, 256, 0, stream>>>(esrc, cnt);
    }
    k_chunk_sum<<<N_CHUNKS, SCAN_BLOCK, 0, stream>>>(cnt, partial);
    k_scan_partial<<<1, 128, 0, stream>>>(partial, row_ptr);
    k_chunk_scan<<<N_CHUNKS, SCAN_BLOCK, 0, stream>>>(cnt, partial, row_ptr);
    if (rank_path) {
        k_fill_rank<<<egrid, 256, 0, stream>>>(esrc, edst, ev, row_ptr, rank, pairs);
    } else {
        k_fill_cur<<<egrid, 256, 0, stream>>>(esrc, edst, ev, row_ptr, cur, pairs);
    }
    k_gather<<<GATHER_BLOCKS, 256, 0, stream>>>(x, row_ptr, pairs, eps, rep);
    k_gemm<<<N_NODES / 32, 256, 0, stream>>>(rep, w, bias, out);
}

// Round 4
// 279.625 us; speedup vs baseline: 1.9335x; 1.1171x over previous
//
#include <hip/hip_runtime.h>

#define N_NODES 100000
#define N_EDGES 1600000
#define D 64
#define SCAN_BLOCK 1024
#define N_CHUNKS ((N_NODES + SCAN_BLOCK - 1) / SCAN_BLOCK)  // 98

// ---- ws layout (4-byte units) ----
#define WS_CNT      0         // [100000] histogram (zeroed)
#define WS_CUR      100000    // [100000] cursor-path cursors (zeroed, cursor path only)
#define WS_ROWPTR   200000    // [100001]
#define WS_PARTIAL  300032    // [128]
#define WS_RANK     300160    // [1600000]  (rank path only)
#define WS_PAIRS_R  1900160   // int2[1600000] rank path  -> needs 20,400,640 B
#define WS_PAIRS_C  300160    // int2[1600000] cursor path -> needs 14,000,640 B

// ---------------- CSR build ----------------

// 8 edges/thread: issue all 8 atomic-returns before any dependent store,
// so each wave has 8 atomics in flight (R2 showed MLP=1 => 71us, VALUBusy 0.5%).
#define HIST_EPT 8
__global__ __launch_bounds__(256) void k_hist_rank(
    const int* __restrict__ esrc, int* __restrict__ cnt, int* __restrict__ rank)
{
    int base = blockIdx.x * (256 * HIST_EPT) + threadIdx.x;
    int s[HIST_EPT];
    #pragma unroll
    for (int i = 0; i < HIST_EPT; ++i) {
        int e = base + i * 256;
        s[i] = (e < N_EDGES) ? esrc[e] : -1;
    }
    int r[HIST_EPT];
    #pragma unroll
    for (int i = 0; i < HIST_EPT; ++i)
        if (s[i] >= 0) r[i] = atomicAdd(&cnt[s[i]], 1);
    #pragma unroll
    for (int i = 0; i < HIST_EPT; ++i) {
        int e = base + i * 256;
        if (e < N_EDGES) rank[e] = r[i];
    }
}

__global__ __launch_bounds__(256) void k_hist(
    const int* __restrict__ esrc, int* __restrict__ cnt)
{
    int e = blockIdx.x * 256 + threadIdx.x;
    if (e < N_EDGES) atomicAdd(&cnt[esrc[e]], 1);
}

__global__ __launch_bounds__(SCAN_BLOCK) void k_chunk_sum(
    const int* __restrict__ cnt, int* __restrict__ partial)
{
    __shared__ int s[16];
    int t = threadIdx.x;
    int i = blockIdx.x * SCAN_BLOCK + t;
    int v = (i < N_NODES) ? cnt[i] : 0;
    #pragma unroll
    for (int off = 32; off; off >>= 1) v += __shfl_down(v, off, 64);
    if ((t & 63) == 0) s[t >> 6] = v;
    __syncthreads();
    if (t < 16) {
        int w = s[t];
        #pragma unroll
        for (int off = 8; off; off >>= 1) w += __shfl_down(w, off, 16);
        if (t == 0) partial[blockIdx.x] = w;
    }
}

__global__ __launch_bounds__(128) void k_scan_partial(
    int* __restrict__ partial, int* __restrict__ row_ptr)
{
    __shared__ int w0;
    int t = threadIdx.x;
    int lane = t & 63;
    int v = (t < N_CHUNKS) ? partial[t] : 0;
    int s = v;
    #pragma unroll
    for (int off = 1; off < 64; off <<= 1) {
        int y = __shfl_up(s, off, 64);
        if (lane >= off) s += y;
    }
    if (t == 63) w0 = s;
    __syncthreads();
    if (t >= 64) s += w0;
    if (t < N_CHUNKS) partial[t] = s - v;
    if (t == N_CHUNKS - 1) row_ptr[N_NODES] = s;
}

__global__ __launch_bounds__(SCAN_BLOCK) void k_chunk_scan(
    const int* __restrict__ cnt, const int* __restrict__ partial,
    int* __restrict__ row_ptr)
{
    __shared__ int wsum[16];
    int t = threadIdx.x;
    int lane = t & 63, wid = t >> 6;
    int i = blockIdx.x * SCAN_BLOCK + t;
    int v = (i < N_NODES) ? cnt[i] : 0;
    int s = v;
    #pragma unroll
    for (int off = 1; off < 64; off <<= 1) {
        int y = __shfl_up(s, off, 64);
        if (lane >= off) s += y;
    }
    if (lane == 63) wsum[wid] = s;
    __syncthreads();
    if (t < 16) {
        int w = wsum[t];
        #pragma unroll
        for (int off = 1; off < 16; off <<= 1) {
            int y = __shfl_up(w, off, 16);
            if (t >= off) w += y;
        }
        wsum[t] = w;
    }
    __syncthreads();
    int prefix = wid ? wsum[wid - 1] : 0;
    if (i < N_NODES) row_ptr[i] = partial[blockIdx.x] + prefix + s - v;
}

// 4 edges/thread for load-level parallelism (row_ptr gather + scattered store).
#define FILL_EPT 4
__global__ __launch_bounds__(256) void k_fill_rank(
    const int* __restrict__ esrc, const int* __restrict__ edst,
    const float* __restrict__ eval_, const int* __restrict__ row_ptr,
    const int* __restrict__ rank, int2* __restrict__ pairs)
{
    int base = blockIdx.x * (256 * FILL_EPT) + threadIdx.x;
    int pos[FILL_EPT]; int2 pv[FILL_EPT];
    #pragma unroll
    for (int i = 0; i < FILL_EPT; ++i) {
        int e = base + i * 256;
        if (e < N_EDGES) {
            pos[i] = row_ptr[esrc[e]] + rank[e];
            pv[i] = make_int2(edst[e], __float_as_int(eval_[e]));
        } else pos[i] = -1;
    }
    #pragma unroll
    for (int i = 0; i < FILL_EPT; ++i)
        if (pos[i] >= 0) pairs[pos[i]] = pv[i];
}

__global__ __launch_bounds__(256) void k_fill_cur(
    const int* __restrict__ esrc, const int* __restrict__ edst,
    const float* __restrict__ eval_, const int* __restrict__ row_ptr,
    int* __restrict__ cur, int2* __restrict__ pairs)
{
    int e = blockIdx.x * 256 + threadIdx.x;
    if (e >= N_EDGES) return;
    int s = esrc[e];
    int pos = row_ptr[s] + atomicAdd(&cur[s], 1);
    pairs[pos] = make_int2(edst[e], __float_as_int(eval_[e]));
}

// ---------------- aggregation: rep = agg + eps*x ----------------
#define GATHER_BLOCKS 1563

__global__ __launch_bounds__(256) void k_gather(
    const float* __restrict__ x, const int* __restrict__ row_ptr,
    const int2* __restrict__ pairs, const float* __restrict__ epsilon,
    float* __restrict__ rep)
{
    int gw = (blockIdx.x * 256 + threadIdx.x) >> 6;
    int lane = threadIdx.x & 63;
    int nw = gridDim.x * 4;
    float eps = epsilon[0];
    for (int row = gw; row < N_NODES; row += nw) {
        int start = __builtin_amdgcn_readfirstlane(row_ptr[row]);
        int end   = __builtin_amdgcn_readfirstlane(row_ptr[row + 1]);
        float acc = 0.0f;
        int j = start;
        for (; j + 8 <= end; j += 8) {
            int2 p[8]; float a[8];
            #pragma unroll
            for (int u = 0; u < 8; ++u) p[u] = pairs[j + u];
            #pragma unroll
            for (int u = 0; u < 8; ++u) a[u] = x[(size_t)p[u].x * D + lane];
            #pragma unroll
            for (int u = 0; u < 8; ++u) acc += __int_as_float(p[u].y) * a[u];
        }
        for (; j + 4 <= end; j += 4) {
            int2 p[4]; float a[4];
            #pragma unroll
            for (int u = 0; u < 4; ++u) p[u] = pairs[j + u];
            #pragma unroll
            for (int u = 0; u < 4; ++u) a[u] = x[(size_t)p[u].x * D + lane];
            #pragma unroll
            for (int u = 0; u < 4; ++u) acc += __int_as_float(p[u].y) * a[u];
        }
        for (; j < end; ++j) {
            int2 p = pairs[j];
            acc += __int_as_float(p.y) * x[(size_t)p.x * D + lane];
        }
        size_t base = (size_t)row * D;
        rep[base + lane] = acc + eps * x[base + lane];
    }
}

// ---------------- out = rep @ W + bias ----------------
// 64-row tile per block, LDS-staged, 4x4 register block per thread.
// rep_s stride 68: bank = (16*ty + 4i + k) % 32 -> 2-way alias only (free).
#define GEMM_TM 64
__global__ __launch_bounds__(256) void k_gemm(
    const float* __restrict__ rep, const float* __restrict__ weight,
    const float* __restrict__ bias, float* __restrict__ out)
{
    __shared__ float rep_s[GEMM_TM * 68];
    __shared__ float Ws[D * D];
    int t = threadIdx.x;
    {
        const float4* w4 = (const float4*)weight;
        float4* s4 = (float4*)Ws;
        #pragma unroll
        for (int i = 0; i < (D * D / 4) / 256; ++i)
            s4[t + i * 256] = w4[t + i * 256];
    }
    int row0 = blockIdx.x * GEMM_TM;
    // stage rep tile: 1024 float4 total, 4 per thread
    {
        const float4* r4 = (const float4*)rep;
        #pragma unroll
        for (int i = 0; i < 4; ++i) {
            int f = t + i * 256;            // float4 index in tile
            int rr = f >> 4, kk4 = f & 15;  // row in tile, float4 col
            float4 v = (row0 + rr < N_NODES) ? r4[(size_t)(row0 + rr) * 16 + kk4]
                                             : make_float4(0.f, 0.f, 0.f, 0.f);
            rep_s[rr * 68 + kk4 * 4 + 0] = v.x;
            rep_s[rr * 68 + kk4 * 4 + 1] = v.y;
            rep_s[rr * 68 + kk4 * 4 + 2] = v.z;
            rep_s[rr * 68 + kk4 * 4 + 3] = v.w;
        }
    }
    __syncthreads();

    int tx = t & 15, ty = t >> 4;          // col group, row group
    float4 b4 = ((const float4*)bias)[tx];
    float acc[4][4];
    #pragma unroll
    for (int i = 0; i < 4; ++i) {
        acc[i][0] = b4.x; acc[i][1] = b4.y; acc[i][2] = b4.z; acc[i][3] = b4.w;
    }
    #pragma unroll 4
    for (int k4 = 0; k4 < 16; ++k4) {
        float4 rv[4];
        #pragma unroll
        for (int i = 0; i < 4; ++i)
            rv[i] = *(const float4*)&rep_s[(ty * 4 + i) * 68 + k4 * 4];
        #pragma unroll
        for (int kk = 0; kk < 4; ++kk) {
            float4 wv = *(const float4*)&Ws[(k4 * 4 + kk) * D + tx * 4];
            #pragma unroll
            for (int i = 0; i < 4; ++i) {
                float r = ((const float*)&rv[i])[kk];
                acc[i][0] += r * wv.x;
                acc[i][1] += r * wv.y;
                acc[i][2] += r * wv.z;
                acc[i][3] += r * wv.w;
            }
        }
    }
    #pragma unroll
    for (int i = 0; i < 4; ++i) {
        int row = row0 + ty * 4 + i;
        if (row < N_NODES)
            *(float4*)&out[(size_t)row * D + tx * 4] =
                make_float4(acc[i][0], acc[i][1], acc[i][2], acc[i][3]);
    }
}

extern "C" void kernel_launch(void* const* d_in, const int* in_sizes, int n_in,
                              void* d_out, int out_size, void* d_ws, size_t ws_size,
                              hipStream_t stream) {
    const float* x    = (const float*)d_in[0];
    const int*   esrc = (const int*)  d_in[1];
    const int*   edst = (const int*)  d_in[2];
    const float* ev   = (const float*)d_in[3];
    const float* w    = (const float*)d_in[4];
    const float* eps  = (const float*)d_in[5];
    const float* bias = (const float*)d_in[6];

    float* out = (float*)d_out;
    float* rep = out + (size_t)N_NODES * D;

    int* ws      = (int*)d_ws;
    int* cnt     = ws + WS_CNT;
    int* cur     = ws + WS_CUR;
    int* row_ptr = ws + WS_ROWPTR;
    int* partial = ws + WS_PARTIAL;

    bool rank_path = ws_size >= (size_t)(WS_PAIRS_R + 2 * N_EDGES) * sizeof(int);
    int* rank   = ws + WS_RANK;
    int2* pairs = (int2*)(ws + (rank_path ? WS_PAIRS_R : WS_PAIRS_C));

    int egrid = (N_EDGES + 255) / 256;

    if (rank_path) {
        hipMemsetAsync(cnt, 0, N_NODES * sizeof(int), stream);
        int hgrid = (N_EDGES + 256 * HIST_EPT - 1) / (256 * HIST_EPT);
        k_hist_rank<<<hgrid, 256, 0, stream>>>(esrc, cnt, rank);
    } else {
        hipMemsetAsync(cnt, 0, 2 * N_NODES * sizeof(int), stream);
        k_hist<<<egrid, 256, 0, stream>>>(esrc, cnt);
    }
    k_chunk_sum<<<N_CHUNKS, SCAN_BLOCK, 0, stream>>>(cnt, partial);
    k_scan_partial<<<1, 128, 0, stream>>>(partial, row_ptr);
    k_chunk_scan<<<N_CHUNKS, SCAN_BLOCK, 0, stream>>>(cnt, partial, row_ptr);
    if (rank_path) {
        int fgrid = (N_EDGES + 256 * FILL_EPT - 1) / (256 * FILL_EPT);
        k_fill_rank<<<fgrid, 256, 0, stream>>>(esrc, edst, ev, row_ptr, rank, pairs);
    } else {
        k_fill_cur<<<egrid, 256, 0, stream>>>(esrc, edst, ev, row_ptr, cur, pairs);
    }
    k_gather<<<GATHER_BLOCKS, 256, 0, stream>>>(x, row_ptr, pairs, eps, rep);
    k_gemm<<<(N_NODES + GEMM_TM - 1) / GEMM_TM, 256, 0, stream>>>(rep, w, bias, out);
}